// Round 10
// baseline (63.984 us; speedup 1.0000x reference)
//
#include <hip/hip_runtime.h>
#include <hip/hip_bf16.h>

#define BDIM 384
#define DDIM 1024
#define LDIM 16
#define WD 300
#define CK 320                 // concepts K padded to 32-multiple for MFMA
#define NROWS (BDIM * LDIM)    // 6144
#define FELEM (BDIM * DDIM)    // 393216
#define SELEM (BDIM * BDIM)    // 147456

typedef __attribute__((ext_vector_type(8))) short short8v;     // 8 bf16
typedef _Float16 half8 __attribute__((ext_vector_type(8)));    // 8 fp16
typedef __attribute__((ext_vector_type(4))) float f32x4;

__device__ inline ushort f2bf(float x) {
    union { float f; unsigned u; } c; c.f = x;
    unsigned u = c.u;
    unsigned r = (u + 0x7fffu + ((u >> 16) & 1u)) >> 16;   // RNE
    return (ushort)r;
}

// ---------------- prep_all: fused prepA-gather | prepB | 3x transW | cvt_m ----------------
#define PRE_A 1920
#define PRE_B (PRE_A + 320)
#define PRE_T (PRE_B + 3072)
#define PRE_M (PRE_T + 384)
__global__ __launch_bounds__(256) void prep_all(
    const float* __restrict__ embed, const int* __restrict__ ntid,
    const int* __restrict__ nlen, const int* __restrict__ ant, const int* __restrict__ t2i,
    ushort* __restrict__ Abf, int* __restrict__ rowtok,
    const float* __restrict__ nW, ushort* __restrict__ BbfT,
    const float* __restrict__ W1, const float* __restrict__ W2, const float* __restrict__ W3,
    _Float16* __restrict__ WT1, _Float16* __restrict__ WT2, _Float16* __restrict__ WT3,
    const float* __restrict__ m, _Float16* __restrict__ mh) {
    __shared__ float tile[32][33];
    const int b = blockIdx.x, t = threadIdx.x;

    if (b < PRE_A) {
        int idx = b * 256 + t;
        int row = idx / (CK / 4);
        int q = idx - row * (CK / 4);
        int tok = ntid[row];
        int w = t2i[tok];
        int eff = (w > 0) ? ant[w] : tok;            // `if weight_idx:` falsy-0 semantics
        bool valid = (row & 15) < nlen[row >> 4];
        if (q == 0) rowtok[row] = valid ? eff : -1;
        ushort4 o = {0, 0, 0, 0};
        if (valid && q < WD / 4) {
            float4 v = *(const float4*)&embed[(size_t)eff * WD + q * 4];
            o.x = f2bf(v.x); o.y = f2bf(v.y); o.z = f2bf(v.z); o.w = f2bf(v.w);
        }
        *(ushort4*)&Abf[(size_t)row * CK + q * 4] = o;
        return;
    }
    if (b < PRE_B) {
        int bb = b - PRE_A;
        const int k0 = (bb % 10) * 32, c0 = (bb / 10) * 32;
        const int r = t >> 3, q = t & 7;
        int k = k0 + r;
        float4 v = {0, 0, 0, 0};
        if (k < WD) v = *(const float4*)&nW[(size_t)k * DDIM + c0 + q * 4];
        tile[r][q * 4 + 0] = v.x; tile[r][q * 4 + 1] = v.y;
        tile[r][q * 4 + 2] = v.z; tile[r][q * 4 + 3] = v.w;
        __syncthreads();
        ushort4 o;
        o.x = f2bf(tile[q * 4 + 0][r]);
        o.y = f2bf(tile[q * 4 + 1][r]);
        o.z = f2bf(tile[q * 4 + 2][r]);
        o.w = f2bf(tile[q * 4 + 3][r]);
        *(ushort4*)&BbfT[(size_t)(c0 + r) * CK + k0 + q * 4] = o;
        return;
    }
    if (b < PRE_T) {
        int bb = b - PRE_B;
        int z = bb >> 10, rem = bb & 1023;
        const float* W = (z == 0) ? W1 : (z == 1) ? W2 : W3;
        _Float16* WT = (z == 0) ? WT1 : (z == 1) ? WT2 : WT3;
        const int k0 = (rem & 31) * 32, c0 = (rem >> 5) * 32;
        const int r = t >> 3, q = t & 7;
        float4 v = *(const float4*)&W[(size_t)(k0 + r) * DDIM + c0 + q * 4];
        tile[r][q * 4 + 0] = v.x; tile[r][q * 4 + 1] = v.y;
        tile[r][q * 4 + 2] = v.z; tile[r][q * 4 + 3] = v.w;
        __syncthreads();
        union { _Float16 h[4]; ushort4 u; } o;
        o.h[0] = (_Float16)tile[q * 4 + 0][r];
        o.h[1] = (_Float16)tile[q * 4 + 1][r];
        o.h[2] = (_Float16)tile[q * 4 + 2][r];
        o.h[3] = (_Float16)tile[q * 4 + 3][r];
        *(ushort4*)&WT[(size_t)(c0 + r) * DDIM + k0 + q * 4] = o.u;
        return;
    }
    {
        int bb = b - PRE_T;
        int i = bb * 1024 + t * 4;
        float4 v = *(const float4*)&m[i];
        union { _Float16 h[4]; ushort4 u; } o;
        o.h[0] = (_Float16)v.x; o.h[1] = (_Float16)v.y;
        o.h[2] = (_Float16)v.z; o.h[3] = (_Float16)v.w;
        *(ushort4*)&mh[i] = o.u;
    }
}

// ---------------- concepts role: 128x128 MFMA bf16, K=CK, dbuf, staged C-write -----------
// cu in [0,384): bm=(cu%48)*128, bn=(cu/48)*128. smem: 69632+512 bytes.
__device__ __forceinline__ void concepts_role(int cu, const ushort* __restrict__ Abf,
                                              const ushort* __restrict__ BbfT,
                                              const int* __restrict__ rowtok,
                                              const float* __restrict__ nbias,
                                              float* __restrict__ C, char* smem) {
    ushort* CAs = (ushort*)smem;                 // [2][5120]
    ushort* CBs = (ushort*)(smem + 20480);       // [2][5120]
    float*  cst = (float*)smem;                  // [2][8704] (aliases; used after K-loop)
    int* stok = (int*)(smem + 69632);

    const int tid = threadIdx.x;
    const int bm = (cu % 48) * 128, bn = (cu / 48) * 128;
    if (tid < 128) stok[tid] = rowtok[bm + tid];

    const int w = tid >> 6, lane = tid & 63;
    const int wrow = (w & 1) * 64, wcol = (w >> 1) * 64;
    const int frow = lane & 15, fk = lane >> 4;
    const int srow = tid >> 2, spart = tid & 3;

    f32x4 acc[4][4];
#pragma unroll
    for (int i = 0; i < 4; ++i)
#pragma unroll
        for (int j = 0; j < 4; ++j) acc[i][j] = (f32x4){0.f, 0.f, 0.f, 0.f};

    int4 pa0, pa1, pb0, pb1;
    constexpr int NK = CK / 32;  // 10

#define C_LOAD(ks)                                                                   \
    {                                                                                \
        const int k0_ = (ks) * 32;                                                   \
        pa0 = *(const int4*)&Abf[(size_t)(bm + srow) * CK + k0_ + spart * 8];        \
        pa1 = *(const int4*)&Abf[(size_t)(bm + 64 + srow) * CK + k0_ + spart * 8];   \
        pb0 = *(const int4*)&BbfT[(size_t)(bn + srow) * CK + k0_ + spart * 8];       \
        pb1 = *(const int4*)&BbfT[(size_t)(bn + 64 + srow) * CK + k0_ + spart * 8];  \
    }
#define C_STORE(buf)                                                                 \
    {                                                                                \
        *(int4*)&CAs[(buf) * 5120 + srow * 40 + spart * 8] = pa0;                    \
        *(int4*)&CAs[(buf) * 5120 + (64 + srow) * 40 + spart * 8] = pa1;             \
        *(int4*)&CBs[(buf) * 5120 + srow * 40 + spart * 8] = pb0;                    \
        *(int4*)&CBs[(buf) * 5120 + (64 + srow) * 40 + spart * 8] = pb1;             \
    }

    C_LOAD(0);
    C_STORE(0);
    __syncthreads();
    int cur = 0;

    for (int ks = 0; ks < NK; ++ks) {
        if (ks + 1 < NK) C_LOAD(ks + 1);
        short8v a[4], b[4];
#pragma unroll
        for (int i = 0; i < 4; ++i)
            a[i] = *(const short8v*)&CAs[cur * 5120 + (wrow + i * 16 + frow) * 40 + fk * 8];
#pragma unroll
        for (int j = 0; j < 4; ++j)
            b[j] = *(const short8v*)&CBs[cur * 5120 + (wcol + j * 16 + frow) * 40 + fk * 8];
#pragma unroll
        for (int i = 0; i < 4; ++i)
#pragma unroll
            for (int j = 0; j < 4; ++j)
                acc[i][j] = __builtin_amdgcn_mfma_f32_16x16x32_bf16(a[i], b[j], acc[i][j], 0, 0, 0);
        if (ks + 1 < NK) C_STORE(cur ^ 1);
        __syncthreads();
        cur ^= 1;
    }
#undef C_LOAD
#undef C_STORE

    const int half = w >> 1;
#pragma unroll
    for (int i = 0; i < 4; ++i)
#pragma unroll
        for (int j = 0; j < 4; ++j)
#pragma unroll
            for (int r2 = 0; r2 < 4; ++r2) {
                int row = wrow + i * 16 + fk * 4 + r2;
                int col = j * 16 + frow;
                cst[half * 8704 + row * 68 + col] = acc[i][j][r2];
            }
    __syncthreads();

#pragma unroll
    for (int it = 0; it < 16; ++it) {
        int f = it * 256 + tid;
        int seg = f & 15;
        int rowh = f >> 4;
        int h2 = rowh >> 7, row = rowh & 127;
        float4 o = *(const float4*)&cst[h2 * 8704 + row * 68 + seg * 4];
        int colb = h2 * 64 + seg * 4;
        float4 bv = *(const float4*)&nbias[bn + colb];
        bool zero = (stok[row] < 0);
        o.x = zero ? 0.f : o.x + bv.x;
        o.y = zero ? 0.f : o.y + bv.y;
        o.z = zero ? 0.f : o.z + bv.z;
        o.w = zero ? 0.f : o.w + bv.w;
        *(float4*)&C[(size_t)(bm + row) * DDIM + bn + colb] = o;
    }
}

// ---------------- em GEMM body (128 thr, 2 waves, 2 accs) — r6 proven ----------------
template <int MODE>
__device__ __forceinline__ void emgemm_body(const _Float16* __restrict__ Ah,
                                            const _Float16* __restrict__ WT,
                                            const float* __restrict__ bias,
                                            float* __restrict__ outF,
                                            _Float16* __restrict__ outH) {
    __shared__ __align__(16) _Float16 As[2][32 * 72];
    __shared__ __align__(16) _Float16 Bs[2][32 * 72];
    const int tid = threadIdx.x;
    const int bm = blockIdx.x * 32, bn = blockIdx.y * 32;
    const int lane = tid & 63;
    const int wrow = (tid >> 6) * 16;
    const int frow = lane & 15, fk = lane >> 4;
    const int srow = tid >> 2, spart = tid & 3;

    f32x4 acc0 = {0.f, 0.f, 0.f, 0.f}, acc1 = {0.f, 0.f, 0.f, 0.f};
    int4 pa0, pa1, pb0, pb1;
    constexpr int NK = DDIM / 64;  // 16

#define E_LOAD(ks)                                                                  \
    {                                                                               \
        const int k0_ = (ks) * 64 + spart * 16;                                     \
        pa0 = *(const int4*)&Ah[(size_t)(bm + srow) * DDIM + k0_];                  \
        pa1 = *(const int4*)&Ah[(size_t)(bm + srow) * DDIM + k0_ + 8];              \
        pb0 = *(const int4*)&WT[(size_t)(bn + srow) * DDIM + k0_];                  \
        pb1 = *(const int4*)&WT[(size_t)(bn + srow) * DDIM + k0_ + 8];              \
    }
#define E_STORE(buf)                                                                \
    {                                                                               \
        *(int4*)&As[buf][srow * 72 + spart * 16] = pa0;                             \
        *(int4*)&As[buf][srow * 72 + spart * 16 + 8] = pa1;                         \
        *(int4*)&Bs[buf][srow * 72 + spart * 16] = pb0;                             \
        *(int4*)&Bs[buf][srow * 72 + spart * 16 + 8] = pb1;                         \
    }

    E_LOAD(0);
    E_STORE(0);
    __syncthreads();
    int cur = 0;

    for (int ks = 0; ks < NK; ++ks) {
        if (ks + 1 < NK) E_LOAD(ks + 1);
#pragma unroll
        for (int kk = 0; kk < 2; ++kk) {
            half8 a = *(const half8*)&As[cur][(wrow + frow) * 72 + kk * 32 + fk * 8];
            half8 b0 = *(const half8*)&Bs[cur][frow * 72 + kk * 32 + fk * 8];
            half8 b1 = *(const half8*)&Bs[cur][(16 + frow) * 72 + kk * 32 + fk * 8];
            acc0 = __builtin_amdgcn_mfma_f32_16x16x32_f16(a, b0, acc0, 0, 0, 0);
            acc1 = __builtin_amdgcn_mfma_f32_16x16x32_f16(a, b1, acc1, 0, 0, 0);
        }
        if (ks + 1 < NK) E_STORE(cur ^ 1);
        __syncthreads();
        cur ^= 1;
    }
#undef E_LOAD
#undef E_STORE

    const int orow0 = bm + wrow + fk * 4;
    const int c0 = bn + frow, c1 = bn + 16 + frow;
    const float b0v = bias[c0], b1v = bias[c1];
#pragma unroll
    for (int r = 0; r < 4; ++r) {
        int row = orow0 + r;
        float v0 = acc0[r] + b0v;
        float v1 = acc1[r] + b1v;
        if (MODE == 1) {
            outH[(size_t)row * DDIM + c0] = (_Float16)fmaxf(v0, 0.f);
            outH[(size_t)row * DDIM + c1] = (_Float16)fmaxf(v1, 0.f);
        } else {
            outF[(size_t)row * DDIM + c0] = v0;
            outF[(size_t)row * DDIM + c1] = v1;
        }
    }
}

// z=0: hh = fp16(relu(mh@WT1+b1)); z=1: Tr = mh@WT3+b3 (f32)
__global__ __launch_bounds__(128) void emgemm13(const _Float16* __restrict__ mh,
                                                const _Float16* __restrict__ WT1,
                                                const _Float16* __restrict__ WT3,
                                                const float* __restrict__ b1,
                                                const float* __restrict__ b3,
                                                _Float16* __restrict__ hh,
                                                float* __restrict__ Tr) {
    if (blockIdx.z == 0)
        emgemm_body<1>(mh, WT1, b1, nullptr, hh);
    else
        emgemm_body<0>(mh, WT3, b3, Tr, nullptr);
}

// ---------------- em GEMM body (256 thr, 4 waves, 1 acc) — r9 proven ----------------
__device__ __forceinline__ void em2_body256(const _Float16* __restrict__ Ah,
                                            const _Float16* __restrict__ WT,
                                            const float* __restrict__ bias,
                                            float* __restrict__ outF,
                                            int bm, int bn,
                                            _Float16* As, _Float16* Bs) {  // each [2][2304]
    const int tid = threadIdx.x;
    const int lane = tid & 63;
    const int w = tid >> 6;
    const int hr = (w & 1) * 16, hc = (w >> 1) * 16;
    const int frow = lane & 15, fk = lane >> 4;
    const int srow = tid >> 3, spart = tid & 7;

    f32x4 acc = {0.f, 0.f, 0.f, 0.f};
    int4 pa, pb;
    constexpr int NK = DDIM / 64;  // 16

#define E2_LOAD(ks)                                                                 \
    {                                                                               \
        const int k0_ = (ks) * 64 + spart * 8;                                      \
        pa = *(const int4*)&Ah[(size_t)(bm + srow) * DDIM + k0_];                   \
        pb = *(const int4*)&WT[(size_t)(bn + srow) * DDIM + k0_];                   \
    }
#define E2_STORE(buf)                                                               \
    {                                                                               \
        *(int4*)&As[(buf) * 2304 + srow * 72 + spart * 8] = pa;                     \
        *(int4*)&Bs[(buf) * 2304 + srow * 72 + spart * 8] = pb;                     \
    }

    E2_LOAD(0);
    E2_STORE(0);
    __syncthreads();
    int cur = 0;

    for (int ks = 0; ks < NK; ++ks) {
        if (ks + 1 < NK) E2_LOAD(ks + 1);
#pragma unroll
        for (int kk = 0; kk < 2; ++kk) {
            half8 a = *(const half8*)&As[cur * 2304 + (hr + frow) * 72 + kk * 32 + fk * 8];
            half8 b = *(const half8*)&Bs[cur * 2304 + (hc + frow) * 72 + kk * 32 + fk * 8];
            acc = __builtin_amdgcn_mfma_f32_16x16x32_f16(a, b, acc, 0, 0, 0);
        }
        if (ks + 1 < NK) E2_STORE(cur ^ 1);
        __syncthreads();
        cur ^= 1;
    }
#undef E2_LOAD
#undef E2_STORE

    const int col = bn + hc + frow;
    const float bv = bias[col];
#pragma unroll
    for (int r2 = 0; r2 < 4; ++r2) {
        int row = bm + hr + fk * 4 + r2;
        outF[(size_t)row * DDIM + col] = acc[r2] + bv;
    }
}

// ---------------- emc: em2 (blocks 0..383) | concepts cu 0..191 (blocks 384..575) --------
__global__ __launch_bounds__(256) void emc(const _Float16* __restrict__ hh,
                                           const _Float16* __restrict__ WT2,
                                           const float* __restrict__ b2,
                                           float* __restrict__ S2,
                                           const ushort* __restrict__ Abf,
                                           const ushort* __restrict__ BbfT,
                                           const int* __restrict__ rowtok,
                                           const float* __restrict__ nbias,
                                           float* __restrict__ C) {
    __shared__ __align__(16) char smem[69632 + 512];
    const int blk = blockIdx.x;
    if (blk < 384) {
        int bm = (blk % 12) * 32, bn = (blk / 12) * 32;
        em2_body256(hh, WT2, b2, S2, bm, bn, (_Float16*)smem, (_Float16*)(smem + 9216));
    } else {
        concepts_role(blk - 384, Abf, BbfT, rowtok, nbias, C, smem);
    }
}

// ---------------- block reductions (256 threads = 4 waves) ----------------
__device__ __forceinline__ float bred_sum(float x, float* sbuf) {
#pragma unroll
    for (int off = 32; off; off >>= 1) x += __shfl_down(x, off);
    __syncthreads();
    if ((threadIdx.x & 63) == 0) sbuf[threadIdx.x >> 6] = x;
    __syncthreads();
    return sbuf[0] + sbuf[1] + sbuf[2] + sbuf[3];
}
__device__ __forceinline__ float bred_max(float x, float* sbuf) {
#pragma unroll
    for (int off = 32; off; off >>= 1) x = fmaxf(x, __shfl_down(x, off));
    __syncthreads();
    if ((threadIdx.x & 63) == 0) sbuf[threadIdx.x >> 6] = x;
    __syncthreads();
    return fmaxf(fmaxf(sbuf[0], sbuf[1]), fmaxf(sbuf[2], sbuf[3]));
}

// ---------------- rowops body (256 thr) — r6 proven ----------------
__device__ __forceinline__ void rowops_body(const float* __restrict__ S2,
                                            const float* __restrict__ Tr,
                                            const float* __restrict__ rr,
                                            const float* __restrict__ tt,
                                            _Float16* __restrict__ uh, _Float16* __restrict__ vh,
                                            _Float16* __restrict__ rh, _Float16* __restrict__ th,
                                            _Float16* __restrict__ t2h,
                                            float* __restrict__ inv_r, float* __restrict__ inv_t,
                                            int b, float* sbuf) {
    const int tid = threadIdx.x;
    const size_t base = (size_t)b * DDIM + tid * 4;

    const float4 s4 = *(const float4*)&S2[base];
    float mx = fmaxf(fmaxf(s4.x, s4.y), fmaxf(s4.z, s4.w));
    mx = bred_max(mx, sbuf);
    float e0 = expf(s4.x - mx), e1 = expf(s4.y - mx), e2 = expf(s4.z - mx), e3 = expf(s4.w - mx);
    float sum = bred_sum(e0 + e1 + e2 + e3, sbuf);
    float invsum = 1.f / sum;

    const float4 tr4 = *(const float4*)&Tr[base];
    float ss = tr4.x * tr4.x + tr4.y * tr4.y + tr4.z * tr4.z + tr4.w * tr4.w;
    ss = bred_sum(ss, sbuf);
    float invn = 1.f / sqrtf(ss);

    float a0 = e0 * invsum, a1 = e1 * invsum, a2 = e2 * invsum, a3 = e3 * invsum;
    union { _Float16 h[4]; ushort4 u; } o;

    o.h[0] = (_Float16)(tr4.x * invn * a0 * 1024.f);
    o.h[1] = (_Float16)(tr4.y * invn * a1 * 1024.f);
    o.h[2] = (_Float16)(tr4.z * invn * a2 * 1024.f);
    o.h[3] = (_Float16)(tr4.w * invn * a3 * 1024.f);
    *(ushort4*)&uh[base] = o.u;

    float q0 = a0 * 32.f, q1 = a1 * 32.f, q2 = a2 * 32.f, q3 = a3 * 32.f;
    o.h[0] = (_Float16)(q0 * q0); o.h[1] = (_Float16)(q1 * q1);
    o.h[2] = (_Float16)(q2 * q2); o.h[3] = (_Float16)(q3 * q3);
    *(ushort4*)&vh[base] = o.u;

    const float4 r4 = *(const float4*)&rr[base];
    o.h[0] = (_Float16)r4.x; o.h[1] = (_Float16)r4.y;
    o.h[2] = (_Float16)r4.z; o.h[3] = (_Float16)r4.w;
    *(ushort4*)&rh[base] = o.u;

    const float4 t4 = *(const float4*)&tt[base];
    o.h[0] = (_Float16)t4.x; o.h[1] = (_Float16)t4.y;
    o.h[2] = (_Float16)t4.z; o.h[3] = (_Float16)t4.w;
    *(ushort4*)&th[base] = o.u;

    o.h[0] = (_Float16)(t4.x * t4.x); o.h[1] = (_Float16)(t4.y * t4.y);
    o.h[2] = (_Float16)(t4.z * t4.z); o.h[3] = (_Float16)(t4.w * t4.w);
    *(ushort4*)&t2h[base] = o.u;

    float sr = bred_sum(r4.x * r4.x + r4.y * r4.y + r4.z * r4.z + r4.w * r4.w, sbuf);
    float st = bred_sum(t4.x * t4.x + t4.y * t4.y + t4.z * t4.z + t4.w * t4.w, sbuf);
    if (tid == 0) {
        inv_r[b] = 1.f / sqrtf(sr);
        inv_t[b] = 1.f / sqrtf(st);
    }
}

// ---------------- rowc: rowops (blocks 0..383) | concepts cu 192..383 (blocks 384..575) ---
__global__ __launch_bounds__(256) void rowc(const float* __restrict__ S2,
                                            const float* __restrict__ Tr,
                                            const float* __restrict__ rr,
                                            const float* __restrict__ tt,
                                            _Float16* __restrict__ uh, _Float16* __restrict__ vh,
                                            _Float16* __restrict__ rh, _Float16* __restrict__ th,
                                            _Float16* __restrict__ t2h,
                                            float* __restrict__ inv_r, float* __restrict__ inv_t,
                                            const ushort* __restrict__ Abf,
                                            const ushort* __restrict__ BbfT,
                                            const int* __restrict__ rowtok,
                                            const float* __restrict__ nbias,
                                            float* __restrict__ C) {
    __shared__ __align__(16) char smem[69632 + 512];
    const int blk = blockIdx.x;
    if (blk < 384) {
        rowops_body(S2, Tr, rr, tt, uh, vh, rh, th, t2h, inv_r, inv_t, blk, (float*)smem);
    } else {
        concepts_role(blk - 384 + 192, Abf, BbfT, rowtok, nbias, C, smem);
    }
}

// ---------------- score: fp16 MFMA, 3 dots, 32x32 tile, K-step 64, dbuf — r6 proven -------
__global__ __launch_bounds__(128) void score_mfma(const _Float16* __restrict__ uh,
                                                  const _Float16* __restrict__ vh,
                                                  const _Float16* __restrict__ rh,
                                                  const _Float16* __restrict__ th,
                                                  const _Float16* __restrict__ t2h,
                                                  const float* __restrict__ inv_r,
                                                  const float* __restrict__ inv_t,
                                                  float* __restrict__ out) {
    __shared__ __align__(16) _Float16 Us[2][32 * 72];
    __shared__ __align__(16) _Float16 Vs[2][32 * 72];
    __shared__ __align__(16) _Float16 Rs[2][32 * 72];
    __shared__ __align__(16) _Float16 Ts[2][32 * 72];
    __shared__ __align__(16) _Float16 Qs[2][32 * 72];

    const int tid = threadIdx.x;
    const int bm = blockIdx.x * 32, bn = blockIdx.y * 32;
    const int lane = tid & 63;
    const int wrow = (tid >> 6) * 16;
    const int frow = lane & 15, fk = lane >> 4;
    const int srow = tid >> 2, spart = tid & 3;

    f32x4 an0 = {0.f, 0.f, 0.f, 0.f}, an1 = an0;
    f32x4 ad0 = an0, ad1 = an0, ai0 = an0, ai1 = an0;
    int4 pu0, pu1, pv0, pv1, pr0, pr1, pt0, pt1, pq0, pq1;
    constexpr int NK = DDIM / 64;  // 16

#define S_LOAD(ks)                                                                   \
    {                                                                                \
        const size_t mo = (size_t)(bm + srow) * DDIM + (ks) * 64 + spart * 16;       \
        const size_t no = (size_t)(bn + srow) * DDIM + (ks) * 64 + spart * 16;       \
        pu0 = *(const int4*)&uh[mo];  pu1 = *(const int4*)&uh[mo + 8];               \
        pv0 = *(const int4*)&vh[mo];  pv1 = *(const int4*)&vh[mo + 8];               \
        pr0 = *(const int4*)&rh[mo];  pr1 = *(const int4*)&rh[mo + 8];               \
        pt0 = *(const int4*)&th[no];  pt1 = *(const int4*)&th[no + 8];               \
        pq0 = *(const int4*)&t2h[no]; pq1 = *(const int4*)&t2h[no + 8];              \
    }
#define S_STORE(buf)                                                                 \
    {                                                                                \
        const int lo = srow * 72 + spart * 16;                                       \
        *(int4*)&Us[buf][lo] = pu0; *(int4*)&Us[buf][lo + 8] = pu1;                  \
        *(int4*)&Vs[buf][lo] = pv0; *(int4*)&Vs[buf][lo + 8] = pv1;                  \
        *(int4*)&Rs[buf][lo] = pr0; *(int4*)&Rs[buf][lo + 8] = pr1;                  \
        *(int4*)&Ts[buf][lo] = pt0; *(int4*)&Ts[buf][lo + 8] = pt1;                  \
        *(int4*)&Qs[buf][lo] = pq0; *(int4*)&Qs[buf][lo + 8] = pq1;                  \
    }

    S_LOAD(0);
    S_STORE(0);
    __syncthreads();
    int cur = 0;

    for (int ks = 0; ks < NK; ++ks) {
        if (ks + 1 < NK) S_LOAD(ks + 1);
#pragma unroll
        for (int kk = 0; kk < 2; ++kk) {
            const int ao = (wrow + frow) * 72 + kk * 32 + fk * 8;
            const int bo0 = frow * 72 + kk * 32 + fk * 8;
            const int bo1 = (16 + frow) * 72 + kk * 32 + fk * 8;
            half8 au = *(const half8*)&Us[cur][ao];
            half8 av = *(const half8*)&Vs[cur][ao];
            half8 ar = *(const half8*)&Rs[cur][ao];
            half8 bt0 = *(const half8*)&Ts[cur][bo0];
            half8 bt1 = *(const half8*)&Ts[cur][bo1];
            half8 bq0 = *(const half8*)&Qs[cur][bo0];
            half8 bq1 = *(const half8*)&Qs[cur][bo1];
            an0 = __builtin_amdgcn_mfma_f32_16x16x32_f16(au, bt0, an0, 0, 0, 0);
            an1 = __builtin_amdgcn_mfma_f32_16x16x32_f16(au, bt1, an1, 0, 0, 0);
            ad0 = __builtin_amdgcn_mfma_f32_16x16x32_f16(av, bq0, ad0, 0, 0, 0);
            ad1 = __builtin_amdgcn_mfma_f32_16x16x32_f16(av, bq1, ad1, 0, 0, 0);
            ai0 = __builtin_amdgcn_mfma_f32_16x16x32_f16(ar, bt0, ai0, 0, 0, 0);
            ai1 = __builtin_amdgcn_mfma_f32_16x16x32_f16(ar, bt1, ai1, 0, 0, 0);
        }
        if (ks + 1 < NK) S_STORE(cur ^ 1);
        __syncthreads();
        cur ^= 1;
    }
#undef S_LOAD
#undef S_STORE

    const int orow0 = bm + wrow + fk * 4;
    const int c0 = bn + frow, c1 = bn + 16 + frow;
    const float it0 = inv_t[c0], it1 = inv_t[c1];
#pragma unroll
    for (int r = 0; r < 4; ++r) {
        int row = orow0 + r;
        float ir = inv_r[row];
        float em0 = an0[r] / (32.f * sqrtf(ad0[r]));
        float em1 = an1[r] / (32.f * sqrtf(ad1[r]));
        out[(size_t)row * BDIM + c0] = em0 + ai0[r] * ir * it0;
        out[(size_t)row * BDIM + c1] = em1 + ai1[r] * ir * it1;
    }
}

extern "C" void kernel_launch(void* const* d_in, const int* in_sizes, int n_in, void* d_out,
                              int out_size, void* d_ws, size_t ws_size, hipStream_t stream) {
    const float* r = (const float*)d_in[0];
    const float* m = (const float*)d_in[1];
    const float* t = (const float*)d_in[2];
    const int* ntid = (const int*)d_in[3];
    const int* nlen = (const int*)d_in[4];
    const int* ant = (const int*)d_in[5];
    const float* embed = (const float*)d_in[6];
    const float* noun_W = (const float*)d_in[7];
    const float* noun_b = (const float*)d_in[8];
    const float* em_W1 = (const float*)d_in[9];
    const float* em_b1 = (const float*)d_in[10];
    const float* em_W2 = (const float*)d_in[11];
    const float* em_b2 = (const float*)d_in[12];
    const float* tr_W = (const float*)d_in[13];
    const float* tr_b = (const float*)d_in[14];
    const int* t2i = (const int*)d_in[15];

    float* score = (float*)d_out;
    float* concepts = score + (size_t)SELEM;

    // ---- flat workspace layout (~19.4 MB; observed ws_size ~268 MB) ----
    char* base = (char*)d_ws;
    size_t off = 0;
    auto alloc = [&](size_t bytes) { char* p = base + off; off += (bytes + 255) & ~(size_t)255; return p; };
    int* rowtok = (int*)alloc(NROWS * 4);
    float* inv_r = (float*)alloc(BDIM * 4);
    float* inv_t = (float*)alloc(BDIM * 4);
    ushort* Abf = (ushort*)alloc((size_t)NROWS * CK * 2);
    ushort* BbfT = (ushort*)alloc((size_t)DDIM * CK * 2);
    _Float16* WT1 = (_Float16*)alloc((size_t)DDIM * DDIM * 2);
    _Float16* WT2 = (_Float16*)alloc((size_t)DDIM * DDIM * 2);
    _Float16* WT3 = (_Float16*)alloc((size_t)DDIM * DDIM * 2);
    _Float16* mh = (_Float16*)alloc((size_t)FELEM * 2);
    _Float16* hh = (_Float16*)alloc((size_t)FELEM * 2);
    float* S2 = (float*)alloc((size_t)FELEM * 4);
    float* Tr = (float*)alloc((size_t)FELEM * 4);
    _Float16* uh = (_Float16*)alloc((size_t)FELEM * 2);
    _Float16* vh = (_Float16*)alloc((size_t)FELEM * 2);
    _Float16* rh = (_Float16*)alloc((size_t)FELEM * 2);
    _Float16* th = (_Float16*)alloc((size_t)FELEM * 2);
    _Float16* t2h = (_Float16*)alloc((size_t)FELEM * 2);

    prep_all<<<PRE_M, 256, 0, stream>>>(embed, ntid, nlen, ant, t2i, Abf, rowtok,
                                        noun_W, BbfT, em_W1, em_W2, tr_W, WT1, WT2, WT3,
                                        m, mh);

    dim3 g13(BDIM / 32, DDIM / 32, 2);  // 12 x 32 x 2
    emgemm13<<<g13, 128, 0, stream>>>(mh, WT1, WT3, em_b1, tr_b, hh, Tr);

    emc<<<576, 256, 0, stream>>>(hh, WT2, em_b2, S2, Abf, BbfT, rowtok, noun_b, concepts);

    rowc<<<576, 256, 0, stream>>>(S2, Tr, r, t, uh, vh, rh, th, t2h, inv_r, inv_t,
                                  Abf, BbfT, rowtok, noun_b, concepts);

    dim3 gS(BDIM / 32, BDIM / 32);      // 12 x 12
    score_mfma<<<gS, 128, 0, stream>>>(uh, vh, rh, th, t2h, inv_r, inv_t, score);
}

// Round 11
// 57.282 us; speedup vs baseline: 1.1170x; 1.1170x over previous
//
#include <hip/hip_runtime.h>
#include <hip/hip_bf16.h>

#define BDIM 384
#define DDIM 1024
#define LDIM 16
#define WD 300
#define CK 320                 // concepts K padded to 32-multiple for MFMA
#define NROWS (BDIM * LDIM)    // 6144
#define FELEM (BDIM * DDIM)    // 393216
#define SELEM (BDIM * BDIM)    // 147456

typedef __attribute__((ext_vector_type(8))) short short8v;     // 8 bf16
typedef _Float16 half8 __attribute__((ext_vector_type(8)));    // 8 fp16
typedef __attribute__((ext_vector_type(4))) float f32x4;

__device__ inline ushort f2bf(float x) {
    union { float f; unsigned u; } c; c.f = x;
    unsigned u = c.u;
    unsigned r = (u + 0x7fffu + ((u >> 16) & 1u)) >> 16;   // RNE
    return (ushort)r;
}

// ---------------- prep_all: fused prepA-gather | prepB | 3x transW | cvt_m ----------------
#define PRE_A 1920
#define PRE_B (PRE_A + 320)
#define PRE_T (PRE_B + 3072)
#define PRE_M (PRE_T + 384)
__global__ __launch_bounds__(256) void prep_all(
    const float* __restrict__ embed, const int* __restrict__ ntid,
    const int* __restrict__ nlen, const int* __restrict__ ant, const int* __restrict__ t2i,
    ushort* __restrict__ Abf, int* __restrict__ rowtok,
    const float* __restrict__ nW, ushort* __restrict__ BbfT,
    const float* __restrict__ W1, const float* __restrict__ W2, const float* __restrict__ W3,
    _Float16* __restrict__ WT1, _Float16* __restrict__ WT2, _Float16* __restrict__ WT3,
    const float* __restrict__ m, _Float16* __restrict__ mh) {
    __shared__ float tile[32][33];
    const int b = blockIdx.x, t = threadIdx.x;

    if (b < PRE_A) {
        int idx = b * 256 + t;
        int row = idx / (CK / 4);
        int q = idx - row * (CK / 4);
        int tok = ntid[row];
        int w = t2i[tok];
        int eff = (w > 0) ? ant[w] : tok;            // `if weight_idx:` falsy-0 semantics
        bool valid = (row & 15) < nlen[row >> 4];
        if (q == 0) rowtok[row] = valid ? eff : -1;
        ushort4 o = {0, 0, 0, 0};
        if (valid && q < WD / 4) {
            float4 v = *(const float4*)&embed[(size_t)eff * WD + q * 4];
            o.x = f2bf(v.x); o.y = f2bf(v.y); o.z = f2bf(v.z); o.w = f2bf(v.w);
        }
        *(ushort4*)&Abf[(size_t)row * CK + q * 4] = o;
        return;
    }
    if (b < PRE_B) {
        int bb = b - PRE_A;
        const int k0 = (bb % 10) * 32, c0 = (bb / 10) * 32;
        const int r = t >> 3, q = t & 7;
        int k = k0 + r;
        float4 v = {0, 0, 0, 0};
        if (k < WD) v = *(const float4*)&nW[(size_t)k * DDIM + c0 + q * 4];
        tile[r][q * 4 + 0] = v.x; tile[r][q * 4 + 1] = v.y;
        tile[r][q * 4 + 2] = v.z; tile[r][q * 4 + 3] = v.w;
        __syncthreads();
        ushort4 o;
        o.x = f2bf(tile[q * 4 + 0][r]);
        o.y = f2bf(tile[q * 4 + 1][r]);
        o.z = f2bf(tile[q * 4 + 2][r]);
        o.w = f2bf(tile[q * 4 + 3][r]);
        *(ushort4*)&BbfT[(size_t)(c0 + r) * CK + k0 + q * 4] = o;
        return;
    }
    if (b < PRE_T) {
        int bb = b - PRE_B;
        int z = bb >> 10, rem = bb & 1023;
        const float* W = (z == 0) ? W1 : (z == 1) ? W2 : W3;
        _Float16* WT = (z == 0) ? WT1 : (z == 1) ? WT2 : WT3;
        const int k0 = (rem & 31) * 32, c0 = (rem >> 5) * 32;
        const int r = t >> 3, q = t & 7;
        float4 v = *(const float4*)&W[(size_t)(k0 + r) * DDIM + c0 + q * 4];
        tile[r][q * 4 + 0] = v.x; tile[r][q * 4 + 1] = v.y;
        tile[r][q * 4 + 2] = v.z; tile[r][q * 4 + 3] = v.w;
        __syncthreads();
        union { _Float16 h[4]; ushort4 u; } o;
        o.h[0] = (_Float16)tile[q * 4 + 0][r];
        o.h[1] = (_Float16)tile[q * 4 + 1][r];
        o.h[2] = (_Float16)tile[q * 4 + 2][r];
        o.h[3] = (_Float16)tile[q * 4 + 3][r];
        *(ushort4*)&WT[(size_t)(c0 + r) * DDIM + k0 + q * 4] = o.u;
        return;
    }
    {
        int bb = b - PRE_T;
        int i = bb * 1024 + t * 4;
        float4 v = *(const float4*)&m[i];
        union { _Float16 h[4]; ushort4 u; } o;
        o.h[0] = (_Float16)v.x; o.h[1] = (_Float16)v.y;
        o.h[2] = (_Float16)v.z; o.h[3] = (_Float16)v.w;
        *(ushort4*)&mh[i] = o.u;
    }
}

// ---------------- em GEMM body (256 thr, 4 waves, 1 acc) — r9/r10 proven ----------------
template <int MODE>
__device__ __forceinline__ void emgemm_body256(const _Float16* __restrict__ Ah,
                                               const _Float16* __restrict__ WT,
                                               const float* __restrict__ bias,
                                               float* __restrict__ outF,
                                               _Float16* __restrict__ outH,
                                               int bm, int bn,
                                               _Float16* As, _Float16* Bs) {  // each [2][2304]
    const int tid = threadIdx.x;
    const int lane = tid & 63;
    const int w = tid >> 6;
    const int hr = (w & 1) * 16, hc = (w >> 1) * 16;
    const int frow = lane & 15, fk = lane >> 4;
    const int srow = tid >> 3, spart = tid & 7;

    f32x4 acc = {0.f, 0.f, 0.f, 0.f};
    int4 pa, pb;
    constexpr int NK = DDIM / 64;  // 16

#define E_LOAD(ks)                                                                  \
    {                                                                               \
        const int k0_ = (ks) * 64 + spart * 8;                                      \
        pa = *(const int4*)&Ah[(size_t)(bm + srow) * DDIM + k0_];                   \
        pb = *(const int4*)&WT[(size_t)(bn + srow) * DDIM + k0_];                   \
    }
#define E_STORE(buf)                                                                \
    {                                                                               \
        *(int4*)&As[(buf) * 2304 + srow * 72 + spart * 8] = pa;                     \
        *(int4*)&Bs[(buf) * 2304 + srow * 72 + spart * 8] = pb;                     \
    }

    E_LOAD(0);
    E_STORE(0);
    __syncthreads();
    int cur = 0;

    for (int ks = 0; ks < NK; ++ks) {
        if (ks + 1 < NK) E_LOAD(ks + 1);
#pragma unroll
        for (int kk = 0; kk < 2; ++kk) {
            half8 a = *(const half8*)&As[cur * 2304 + (hr + frow) * 72 + kk * 32 + fk * 8];
            half8 b = *(const half8*)&Bs[cur * 2304 + (hc + frow) * 72 + kk * 32 + fk * 8];
            acc = __builtin_amdgcn_mfma_f32_16x16x32_f16(a, b, acc, 0, 0, 0);
        }
        if (ks + 1 < NK) E_STORE(cur ^ 1);
        __syncthreads();
        cur ^= 1;
    }
#undef E_LOAD
#undef E_STORE

    const int col = bn + hc + frow;
    const float bv = bias[col];
#pragma unroll
    for (int r2 = 0; r2 < 4; ++r2) {
        int row = bm + hr + fk * 4 + r2;
        float v = acc[r2] + bv;
        if (MODE == 1)
            outH[(size_t)row * DDIM + col] = (_Float16)fmaxf(v, 0.f);
        else
            outF[(size_t)row * DDIM + col] = v;
    }
}

// ---------------- concepts64: 64x64 MFMA bf16 tile, K=CK, dbuf, 20.5KB LDS ----------------
// cu in [0,1536): bm=(cu%96)*64, bn=(cu/96)*64. Derived from the r3-r6-proven 128-tile body
// (same 40-ushort stride, same fragment indexing), dims halved so the role no longer caps
// co-resident occupancy (20.5KB vs 70KB).
__device__ __forceinline__ void concepts64(int cu, const ushort* __restrict__ Abf,
                                           const ushort* __restrict__ BbfT,
                                           const int* __restrict__ rowtok,
                                           const float* __restrict__ nbias,
                                           float* __restrict__ C, char* smem) {
    ushort* CAs = (ushort*)smem;                 // [2][2560]
    ushort* CBs = (ushort*)(smem + 10240);       // [2][2560]
    float*  cst = (float*)smem;                  // [64*68] = 17408B (aliases after K-loop)
    int* stok = (int*)(smem + 20480);            // [64]

    const int tid = threadIdx.x;
    const int bm = (cu % 96) * 64, bn = (cu / 96) * 64;
    if (tid < 64) stok[tid] = rowtok[bm + tid];

    const int w = tid >> 6, lane = tid & 63;
    const int wr = (w & 1) * 32, wc = (w >> 1) * 32;
    const int frow = lane & 15, fk = lane >> 4;
    const int srow = tid >> 2, spart = tid & 3;

    f32x4 acc[2][2];
#pragma unroll
    for (int i = 0; i < 2; ++i)
#pragma unroll
        for (int j = 0; j < 2; ++j) acc[i][j] = (f32x4){0.f, 0.f, 0.f, 0.f};

    int4 pa, pb;
    constexpr int NK = CK / 32;  // 10

#define C_LOAD(ks)                                                                   \
    {                                                                                \
        const int k0_ = (ks) * 32;                                                   \
        pa = *(const int4*)&Abf[(size_t)(bm + srow) * CK + k0_ + spart * 8];         \
        pb = *(const int4*)&BbfT[(size_t)(bn + srow) * CK + k0_ + spart * 8];        \
    }
#define C_STORE(buf)                                                                 \
    {                                                                                \
        *(int4*)&CAs[(buf) * 2560 + srow * 40 + spart * 8] = pa;                     \
        *(int4*)&CBs[(buf) * 2560 + srow * 40 + spart * 8] = pb;                     \
    }

    C_LOAD(0);
    C_STORE(0);
    __syncthreads();
    int cur = 0;

    for (int ks = 0; ks < NK; ++ks) {
        if (ks + 1 < NK) C_LOAD(ks + 1);
        short8v a[2], b[2];
#pragma unroll
        for (int i = 0; i < 2; ++i)
            a[i] = *(const short8v*)&CAs[cur * 2560 + (wr + i * 16 + frow) * 40 + fk * 8];
#pragma unroll
        for (int j = 0; j < 2; ++j)
            b[j] = *(const short8v*)&CBs[cur * 2560 + (wc + j * 16 + frow) * 40 + fk * 8];
#pragma unroll
        for (int i = 0; i < 2; ++i)
#pragma unroll
            for (int j = 0; j < 2; ++j)
                acc[i][j] = __builtin_amdgcn_mfma_f32_16x16x32_bf16(a[i], b[j], acc[i][j], 0, 0, 0);
        if (ks + 1 < NK) C_STORE(cur ^ 1);
        __syncthreads();
        cur ^= 1;
    }
#undef C_LOAD
#undef C_STORE

    // staged epilogue: acc -> cst (f32, stride 68; 2-way bank alias = free) -> float4 stores
#pragma unroll
    for (int i = 0; i < 2; ++i)
#pragma unroll
        for (int j = 0; j < 2; ++j)
#pragma unroll
            for (int r2 = 0; r2 < 4; ++r2) {
                int row = wr + i * 16 + fk * 4 + r2;
                int col = wc + j * 16 + frow;
                cst[row * 68 + col] = acc[i][j][r2];
            }
    __syncthreads();

#pragma unroll
    for (int it = 0; it < 4; ++it) {
        int f = it * 256 + tid;          // 1024 float4 total
        int seg = f & 15;
        int row = f >> 4;
        float4 o = *(const float4*)&cst[row * 68 + seg * 4];
        int colb = seg * 4;
        float4 bv = *(const float4*)&nbias[bn + colb];
        bool zero = (stok[row] < 0);
        o.x = zero ? 0.f : o.x + bv.x;
        o.y = zero ? 0.f : o.y + bv.y;
        o.z = zero ? 0.f : o.z + bv.z;
        o.w = zero ? 0.f : o.w + bv.w;
        *(float4*)&C[(size_t)(bm + row) * DDIM + bn + colb] = o;
    }
}

// ---------------- mega1: em1 (0..383) | Tr (384..767) | concepts64 (768..2303) ----------
__global__ __launch_bounds__(256) void mega1(const _Float16* __restrict__ mh,
                                             const _Float16* __restrict__ WT1,
                                             const _Float16* __restrict__ WT3,
                                             const float* __restrict__ b1,
                                             const float* __restrict__ b3,
                                             _Float16* __restrict__ hh,
                                             float* __restrict__ Tr,
                                             const ushort* __restrict__ Abf,
                                             const ushort* __restrict__ BbfT,
                                             const int* __restrict__ rowtok,
                                             const float* __restrict__ nbias,
                                             float* __restrict__ C) {
    __shared__ __align__(16) char smem[20480 + 256];
    const int blk = blockIdx.x;
    if (blk < 384) {
        int bm = (blk % 12) * 32, bn = (blk / 12) * 32;
        emgemm_body256<1>(mh, WT1, b1, nullptr, hh, bm, bn,
                          (_Float16*)smem, (_Float16*)(smem + 9216));
    } else if (blk < 768) {
        int v = blk - 384;
        int bm = (v % 12) * 32, bn = (v / 12) * 32;
        emgemm_body256<0>(mh, WT3, b3, Tr, nullptr, bm, bn,
                          (_Float16*)smem, (_Float16*)(smem + 9216));
    } else {
        concepts64(blk - 768, Abf, BbfT, rowtok, nbias, C, smem);
    }
}

// ---------------- em2k: S2 = hh @ WT2 + b2 (f32) ----------------
__global__ __launch_bounds__(256) void em2k(const _Float16* __restrict__ hh,
                                            const _Float16* __restrict__ WT2,
                                            const float* __restrict__ b2,
                                            float* __restrict__ S2) {
    __shared__ __align__(16) _Float16 As[2 * 2304];
    __shared__ __align__(16) _Float16 Bs[2 * 2304];
    int u = blockIdx.x;
    int bm = (u % 12) * 32, bn = (u / 12) * 32;
    emgemm_body256<0>(hh, WT2, b2, S2, nullptr, bm, bn, As, Bs);
}

// ---------------- block reductions (256 threads = 4 waves) ----------------
__device__ __forceinline__ float bred_sum(float x, float* sbuf) {
#pragma unroll
    for (int off = 32; off; off >>= 1) x += __shfl_down(x, off);
    __syncthreads();
    if ((threadIdx.x & 63) == 0) sbuf[threadIdx.x >> 6] = x;
    __syncthreads();
    return sbuf[0] + sbuf[1] + sbuf[2] + sbuf[3];
}
__device__ __forceinline__ float bred_max(float x, float* sbuf) {
#pragma unroll
    for (int off = 32; off; off >>= 1) x = fmaxf(x, __shfl_down(x, off));
    __syncthreads();
    if ((threadIdx.x & 63) == 0) sbuf[threadIdx.x >> 6] = x;
    __syncthreads();
    return fmaxf(fmaxf(sbuf[0], sbuf[1]), fmaxf(sbuf[2], sbuf[3]));
}

// ---------------- rowops: softmax(S2), l2norm(Tr) -> fp16 uh,vh,rh,th,t2h; inv norms ----
__global__ __launch_bounds__(256) void rowops(const float* __restrict__ S2,
                                              const float* __restrict__ Tr,
                                              const float* __restrict__ rr,
                                              const float* __restrict__ tt,
                                              _Float16* __restrict__ uh, _Float16* __restrict__ vh,
                                              _Float16* __restrict__ rh, _Float16* __restrict__ th,
                                              _Float16* __restrict__ t2h,
                                              float* __restrict__ inv_r,
                                              float* __restrict__ inv_t) {
    __shared__ float sbuf[4];
    const int b = blockIdx.x, tid = threadIdx.x;
    const size_t base = (size_t)b * DDIM + tid * 4;

    const float4 s4 = *(const float4*)&S2[base];
    float mx = fmaxf(fmaxf(s4.x, s4.y), fmaxf(s4.z, s4.w));
    mx = bred_max(mx, sbuf);
    float e0 = expf(s4.x - mx), e1 = expf(s4.y - mx), e2 = expf(s4.z - mx), e3 = expf(s4.w - mx);
    float sum = bred_sum(e0 + e1 + e2 + e3, sbuf);
    float invsum = 1.f / sum;

    const float4 tr4 = *(const float4*)&Tr[base];
    float ss = tr4.x * tr4.x + tr4.y * tr4.y + tr4.z * tr4.z + tr4.w * tr4.w;
    ss = bred_sum(ss, sbuf);
    float invn = 1.f / sqrtf(ss);

    float a0 = e0 * invsum, a1 = e1 * invsum, a2 = e2 * invsum, a3 = e3 * invsum;
    union { _Float16 h[4]; ushort4 u; } o;

    o.h[0] = (_Float16)(tr4.x * invn * a0 * 1024.f);
    o.h[1] = (_Float16)(tr4.y * invn * a1 * 1024.f);
    o.h[2] = (_Float16)(tr4.z * invn * a2 * 1024.f);
    o.h[3] = (_Float16)(tr4.w * invn * a3 * 1024.f);
    *(ushort4*)&uh[base] = o.u;

    float q0 = a0 * 32.f, q1 = a1 * 32.f, q2 = a2 * 32.f, q3 = a3 * 32.f;
    o.h[0] = (_Float16)(q0 * q0); o.h[1] = (_Float16)(q1 * q1);
    o.h[2] = (_Float16)(q2 * q2); o.h[3] = (_Float16)(q3 * q3);
    *(ushort4*)&vh[base] = o.u;

    const float4 r4 = *(const float4*)&rr[base];
    o.h[0] = (_Float16)r4.x; o.h[1] = (_Float16)r4.y;
    o.h[2] = (_Float16)r4.z; o.h[3] = (_Float16)r4.w;
    *(ushort4*)&rh[base] = o.u;

    const float4 t4 = *(const float4*)&tt[base];
    o.h[0] = (_Float16)t4.x; o.h[1] = (_Float16)t4.y;
    o.h[2] = (_Float16)t4.z; o.h[3] = (_Float16)t4.w;
    *(ushort4*)&th[base] = o.u;

    o.h[0] = (_Float16)(t4.x * t4.x); o.h[1] = (_Float16)(t4.y * t4.y);
    o.h[2] = (_Float16)(t4.z * t4.z); o.h[3] = (_Float16)(t4.w * t4.w);
    *(ushort4*)&t2h[base] = o.u;

    float sr = bred_sum(r4.x * r4.x + r4.y * r4.y + r4.z * r4.z + r4.w * r4.w, sbuf);
    float st = bred_sum(t4.x * t4.x + t4.y * t4.y + t4.z * t4.z + t4.w * t4.w, sbuf);
    if (tid == 0) {
        inv_r[b] = 1.f / sqrtf(sr);
        inv_t[b] = 1.f / sqrtf(st);
    }
}

// ---------------- score: fp16 MFMA, 3 dots, 32x32 tile, K-step 64, dbuf — r6 proven -------
__global__ __launch_bounds__(128) void score_mfma(const _Float16* __restrict__ uh,
                                                  const _Float16* __restrict__ vh,
                                                  const _Float16* __restrict__ rh,
                                                  const _Float16* __restrict__ th,
                                                  const _Float16* __restrict__ t2h,
                                                  const float* __restrict__ inv_r,
                                                  const float* __restrict__ inv_t,
                                                  float* __restrict__ out) {
    __shared__ __align__(16) _Float16 Us[2][32 * 72];
    __shared__ __align__(16) _Float16 Vs[2][32 * 72];
    __shared__ __align__(16) _Float16 Rs[2][32 * 72];
    __shared__ __align__(16) _Float16 Ts[2][32 * 72];
    __shared__ __align__(16) _Float16 Qs[2][32 * 72];

    const int tid = threadIdx.x;
    const int bm = blockIdx.x * 32, bn = blockIdx.y * 32;
    const int lane = tid & 63;
    const int wrow = (tid >> 6) * 16;
    const int frow = lane & 15, fk = lane >> 4;
    const int srow = tid >> 2, spart = tid & 3;

    f32x4 an0 = {0.f, 0.f, 0.f, 0.f}, an1 = an0;
    f32x4 ad0 = an0, ad1 = an0, ai0 = an0, ai1 = an0;
    int4 pu0, pu1, pv0, pv1, pr0, pr1, pt0, pt1, pq0, pq1;
    constexpr int NK = DDIM / 64;  // 16

#define S_LOAD(ks)                                                                   \
    {                                                                                \
        const size_t mo = (size_t)(bm + srow) * DDIM + (ks) * 64 + spart * 16;       \
        const size_t no = (size_t)(bn + srow) * DDIM + (ks) * 64 + spart * 16;       \
        pu0 = *(const int4*)&uh[mo];  pu1 = *(const int4*)&uh[mo + 8];               \
        pv0 = *(const int4*)&vh[mo];  pv1 = *(const int4*)&vh[mo + 8];               \
        pr0 = *(const int4*)&rh[mo];  pr1 = *(const int4*)&rh[mo + 8];               \
        pt0 = *(const int4*)&th[no];  pt1 = *(const int4*)&th[no + 8];               \
        pq0 = *(const int4*)&t2h[no]; pq1 = *(const int4*)&t2h[no + 8];              \
    }
#define S_STORE(buf)                                                                 \
    {                                                                                \
        const int lo = srow * 72 + spart * 16;                                       \
        *(int4*)&Us[buf][lo] = pu0; *(int4*)&Us[buf][lo + 8] = pu1;                  \
        *(int4*)&Vs[buf][lo] = pv0; *(int4*)&Vs[buf][lo + 8] = pv1;                  \
        *(int4*)&Rs[buf][lo] = pr0; *(int4*)&Rs[buf][lo + 8] = pr1;                  \
        *(int4*)&Ts[buf][lo] = pt0; *(int4*)&Ts[buf][lo + 8] = pt1;                  \
        *(int4*)&Qs[buf][lo] = pq0; *(int4*)&Qs[buf][lo + 8] = pq1;                  \
    }

    S_LOAD(0);
    S_STORE(0);
    __syncthreads();
    int cur = 0;

    for (int ks = 0; ks < NK; ++ks) {
        if (ks + 1 < NK) S_LOAD(ks + 1);
#pragma unroll
        for (int kk = 0; kk < 2; ++kk) {
            const int ao = (wrow + frow) * 72 + kk * 32 + fk * 8;
            const int bo0 = frow * 72 + kk * 32 + fk * 8;
            const int bo1 = (16 + frow) * 72 + kk * 32 + fk * 8;
            half8 au = *(const half8*)&Us[cur][ao];
            half8 av = *(const half8*)&Vs[cur][ao];
            half8 ar = *(const half8*)&Rs[cur][ao];
            half8 bt0 = *(const half8*)&Ts[cur][bo0];
            half8 bt1 = *(const half8*)&Ts[cur][bo1];
            half8 bq0 = *(const half8*)&Qs[cur][bo0];
            half8 bq1 = *(const half8*)&Qs[cur][bo1];
            an0 = __builtin_amdgcn_mfma_f32_16x16x32_f16(au, bt0, an0, 0, 0, 0);
            an1 = __builtin_amdgcn_mfma_f32_16x16x32_f16(au, bt1, an1, 0, 0, 0);
            ad0 = __builtin_amdgcn_mfma_f32_16x16x32_f16(av, bq0, ad0, 0, 0, 0);
            ad1 = __builtin_amdgcn_mfma_f32_16x16x32_f16(av, bq1, ad1, 0, 0, 0);
            ai0 = __builtin_amdgcn_mfma_f32_16x16x32_f16(ar, bt0, ai0, 0, 0, 0);
            ai1 = __builtin_amdgcn_mfma_f32_16x16x32_f16(ar, bt1, ai1, 0, 0, 0);
        }
        if (ks + 1 < NK) S_STORE(cur ^ 1);
        __syncthreads();
        cur ^= 1;
    }
#undef S_LOAD
#undef S_STORE

    const int orow0 = bm + wrow + fk * 4;
    const int c0 = bn + frow, c1 = bn + 16 + frow;
    const float it0 = inv_t[c0], it1 = inv_t[c1];
#pragma unroll
    for (int r = 0; r < 4; ++r) {
        int row = orow0 + r;
        float ir = inv_r[row];
        float em0 = an0[r] / (32.f * sqrtf(ad0[r]));
        float em1 = an1[r] / (32.f * sqrtf(ad1[r]));
        out[(size_t)row * BDIM + c0] = em0 + ai0[r] * ir * it0;
        out[(size_t)row * BDIM + c1] = em1 + ai1[r] * ir * it1;
    }
}

extern "C" void kernel_launch(void* const* d_in, const int* in_sizes, int n_in, void* d_out,
                              int out_size, void* d_ws, size_t ws_size, hipStream_t stream) {
    const float* r = (const float*)d_in[0];
    const float* m = (const float*)d_in[1];
    const float* t = (const float*)d_in[2];
    const int* ntid = (const int*)d_in[3];
    const int* nlen = (const int*)d_in[4];
    const int* ant = (const int*)d_in[5];
    const float* embed = (const float*)d_in[6];
    const float* noun_W = (const float*)d_in[7];
    const float* noun_b = (const float*)d_in[8];
    const float* em_W1 = (const float*)d_in[9];
    const float* em_b1 = (const float*)d_in[10];
    const float* em_W2 = (const float*)d_in[11];
    const float* em_b2 = (const float*)d_in[12];
    const float* tr_W = (const float*)d_in[13];
    const float* tr_b = (const float*)d_in[14];
    const int* t2i = (const int*)d_in[15];

    float* score = (float*)d_out;
    float* concepts = score + (size_t)SELEM;

    // ---- flat workspace layout (~19.4 MB; observed ws_size ~268 MB) ----
    char* base = (char*)d_ws;
    size_t off = 0;
    auto alloc = [&](size_t bytes) { char* p = base + off; off += (bytes + 255) & ~(size_t)255; return p; };
    int* rowtok = (int*)alloc(NROWS * 4);
    float* inv_r = (float*)alloc(BDIM * 4);
    float* inv_t = (float*)alloc(BDIM * 4);
    ushort* Abf = (ushort*)alloc((size_t)NROWS * CK * 2);
    ushort* BbfT = (ushort*)alloc((size_t)DDIM * CK * 2);
    _Float16* WT1 = (_Float16*)alloc((size_t)DDIM * DDIM * 2);
    _Float16* WT2 = (_Float16*)alloc((size_t)DDIM * DDIM * 2);
    _Float16* WT3 = (_Float16*)alloc((size_t)DDIM * DDIM * 2);
    _Float16* mh = (_Float16*)alloc((size_t)FELEM * 2);
    _Float16* hh = (_Float16*)alloc((size_t)FELEM * 2);
    float* S2 = (float*)alloc((size_t)FELEM * 4);
    float* Tr = (float*)alloc((size_t)FELEM * 4);
    _Float16* uh = (_Float16*)alloc((size_t)FELEM * 2);
    _Float16* vh = (_Float16*)alloc((size_t)FELEM * 2);
    _Float16* rh = (_Float16*)alloc((size_t)FELEM * 2);
    _Float16* th = (_Float16*)alloc((size_t)FELEM * 2);
    _Float16* t2h = (_Float16*)alloc((size_t)FELEM * 2);

    prep_all<<<PRE_M, 256, 0, stream>>>(embed, ntid, nlen, ant, t2i, Abf, rowtok,
                                        noun_W, BbfT, em_W1, em_W2, tr_W, WT1, WT2, WT3,
                                        m, mh);

    mega1<<<2304, 256, 0, stream>>>(mh, WT1, WT3, em_b1, tr_b, hh, Tr,
                                    Abf, BbfT, rowtok, noun_b, concepts);

    em2k<<<384, 256, 0, stream>>>(hh, WT2, em_b2, S2);

    rowops<<<BDIM, 256, 0, stream>>>(S2, Tr, r, t, uh, vh, rh, th, t2h, inv_r, inv_t);

    dim3 gS(BDIM / 32, BDIM / 32);      // 12 x 12
    score_mfma<<<gS, 128, 0, stream>>>(uh, vh, rh, th, t2h, inv_r, inv_t, score);
}